// Round 8
// baseline (196.280 us; speedup 1.0000x reference)
//
#include <hip/hip_runtime.h>
#include <hip/hip_bf16.h>

#define B_ 1024
#define P_ 8
#define D_ 2048
#define FD_ (P_ * D_)   // 16384
#define NID 64
#define MARGIN_ 0.3f
#define EPS_ 1e-12f

typedef unsigned short u16;
typedef float float4_t __attribute__((ext_vector_type(4)));

__device__ __forceinline__ float bf2f(unsigned v) {
    unsigned x = v << 16;
    float f;
    __builtin_memcpy(&f, &x, 4);
    return f;
}

// ---------------- workspace layout (bytes) ----------------
static const size_t OFF_COUNTS = 0;         // 64 fp32
static const size_t OFF_OFFS   = 256;       // 64 int
static const size_t OFF_PERM   = 512;       // 1024 int -> ends 4608
static const size_t OFF_NEG    = 4608;
static const size_t OFF_POS    = 8168;      // memset region starts here
static const size_t OFF_TICKET = 8172;      // int, zeroed by same memset
static const size_t OFF_S      = 8192;      // 1024*8 fp32 = 32 KB -> 40960 (memset)
static const size_t OFF_SQ     = 40960;     // 1024*8 fp32
static const size_t OFF_DAP    = 73728;     // 1024 fp32
static const size_t OFF_FB     = 131072;    // fragment-ordered fp8, 16 MB (see below)
static const size_t OFF_PD     = OFF_FB + (size_t)B_ * FD_;  // 8 planes * 1024*1024 bf16

// fb fragment-order layout: plane p (2 MB), row-group rb = row/16 (64), k-step ks = k/32
// (64), lane = lhi*16 + llo; 8-byte chunk at
//   p*2097152 + rb*32768 + ks*512 + lane*8
// holds row (rb*16+llo), fp8 k-bytes [ks*32 + lhi*8, +8) — exactly one wave fragment
// per contiguous 512 B.

// ---------------- kernel 1: fp8 cast to fragment order + sq; last block = counts -------
// grid 513 x 256: id < 512 -> p = id&7 (XCD match), rb = id>>3; id == 512 -> counts.
__global__ void k_prep(const float* __restrict__ feats, const int* __restrict__ labels,
                       unsigned char* __restrict__ fb, float* __restrict__ sq,
                       float* countsf, int* offs, int* perm, float* negcnt) {
    int tid = threadIdx.x;
    __shared__ __align__(16) unsigned char st[32768];
    if (blockIdx.x < 512) {
        const int p = blockIdx.x & 7;
        const int rb = blockIdx.x >> 3;
        const int r = tid >> 4;    // row within group, 0..15
        const int s = tid & 15;    // 16 threads per row
        const int i = rb * 16 + r;
        const float* frow = feats + (size_t)i * FD_ + p * D_;
        const int ks_lo = (s >> 1);       // ks = it*8 + ks_lo
        const int lhi0 = (s & 1) * 2;     // chunks lhi0, lhi0+1
        float s2 = 0.f;
#pragma unroll
        for (int it = 0; it < 8; it++) {
            int d = it * 256 + s * 16;
            float4 f0 = *(const float4*)(frow + d);
            float4 f1 = *(const float4*)(frow + d + 4);
            float4 f2 = *(const float4*)(frow + d + 8);
            float4 f3 = *(const float4*)(frow + d + 12);
            s2 += f0.x*f0.x + f0.y*f0.y + f0.z*f0.z + f0.w*f0.w
                + f1.x*f1.x + f1.y*f1.y + f1.z*f1.z + f1.w*f1.w
                + f2.x*f2.x + f2.y*f2.y + f2.z*f2.z + f2.w*f2.w
                + f3.x*f3.x + f3.y*f3.y + f3.z*f3.z + f3.w*f3.w;
            unsigned u0 = (unsigned)__builtin_amdgcn_cvt_pk_fp8_f32(f0.x, f0.y, 0, false);
            u0 = (unsigned)__builtin_amdgcn_cvt_pk_fp8_f32(f0.z, f0.w, (int)u0, true);
            unsigned u1 = (unsigned)__builtin_amdgcn_cvt_pk_fp8_f32(f1.x, f1.y, 0, false);
            u1 = (unsigned)__builtin_amdgcn_cvt_pk_fp8_f32(f1.z, f1.w, (int)u1, true);
            unsigned u2 = (unsigned)__builtin_amdgcn_cvt_pk_fp8_f32(f2.x, f2.y, 0, false);
            u2 = (unsigned)__builtin_amdgcn_cvt_pk_fp8_f32(f2.z, f2.w, (int)u2, true);
            unsigned u3 = (unsigned)__builtin_amdgcn_cvt_pk_fp8_f32(f3.x, f3.y, 0, false);
            u3 = (unsigned)__builtin_amdgcn_cvt_pk_fp8_f32(f3.z, f3.w, (int)u3, true);
            int ks = it * 8 + ks_lo;
            // chunk addr (elements): ks*512 + lhi*128 + r*8
            *(uint2*)&st[ks * 512 + lhi0 * 128 + r * 8] = make_uint2(u0, u1);
            *(uint2*)&st[ks * 512 + (lhi0 + 1) * 128 + r * 8] = make_uint2(u2, u3);
        }
        // sq reduce over the 16 threads of this row (lanes share upper bits)
        s2 += __shfl_xor(s2, 1, 64);
        s2 += __shfl_xor(s2, 2, 64);
        s2 += __shfl_xor(s2, 4, 64);
        s2 += __shfl_xor(s2, 8, 64);
        if (s == 0) sq[i * 8 + p] = s2;
        __syncthreads();
        // coalesced copy LDS -> fb
        unsigned char* dst = fb + (size_t)p * 2097152 + (size_t)rb * 32768;
#pragma unroll
        for (int c = 0; c < 8; c++) {
            int off = tid * 128 + c * 16;
            *(uint4*)(dst + off) = *(const uint4*)&st[off];
        }
    } else {
        // counts + prefix + perm + negcnt
        __shared__ int h[NID], o[NID], cur[NID];
        if (tid < NID) h[tid] = 0;
        __syncthreads();
        for (int i = tid; i < B_; i += 256) atomicAdd(&h[labels[i]], 1);
        __syncthreads();
        if (tid == 0) {
            int acc = 0;
            long long ss = 0;
            for (int c = 0; c < NID; c++) {
                o[c] = acc;
                acc += h[c];
                ss += (long long)h[c] * h[c];
            }
            *negcnt = (float)((long long)B_ * B_ - ss);
        }
        __syncthreads();
        if (tid < NID) {
            countsf[tid] = (float)h[tid];
            offs[tid] = o[tid];
            cur[tid] = o[tid];
        }
        __syncthreads();
        for (int i = tid; i < B_; i += 256) {
            int pos = atomicAdd(&cur[labels[i]], 1);
            perm[pos] = i;
        }
    }
}

// ---------------- kernel 2: barrier-free fp8 MFMA pair kernel ----------------
// grid (8, 136): x = plane p (XCD = id%8), y = triangle item -> (tu, tv), tv >= tu,
// 64x64 tile at i0 = tu*64, j0 = tv*64. block 128 = 2 waves = 2 K-halves of the item.
// K-loop: 8 coalesced 512-B fragment loads + 16 MFMA per ks, NO barriers (loads stay
// in flight under compiler vmcnt(N)). One barrier at end to combine halves via LDS.
// Epilogue: sqrt -> bf16 pd; label-masked row sums -> S[i]; col sums -> S[j] (tv>tu).
__global__ __launch_bounds__(128) void k_pairs(const unsigned char* __restrict__ fb,
                                               const float* __restrict__ sq,
                                               const int* __restrict__ labels,
                                               float* __restrict__ S,
                                               u16* __restrict__ pd) {
    const int p = blockIdx.x;
    int rem = blockIdx.y, tu = 0;
    while (rem >= 16 - tu) { rem -= 16 - tu; tu++; }
    const int tv = tu + rem;
    const int i0 = tu * 64, j0 = tv * 64;

    __shared__ __align__(16) float ep[4096];  // 16 KB combine buffer
    __shared__ float sqAs[64], sqBs[64];
    __shared__ int labA[64], labB[64];
    const int tid = threadIdx.x;
    const int lane = tid & 63;
    const int h = tid >> 6;  // K-half
    if (tid < 64) {
        sqAs[tid] = sq[(i0 + tid) * 8 + p];
        labA[tid] = labels[i0 + tid];
    } else {
        sqBs[lane] = sq[(j0 + lane) * 8 + p];
        labB[lane] = labels[j0 + lane];
    }

    const unsigned char* base = fb + (size_t)p * 2097152 + (size_t)lane * 8;
    const unsigned char* pA[4];
    const unsigned char* pB[4];
#pragma unroll
    for (int a = 0; a < 4; a++) {
        pA[a] = base + (size_t)(tu * 4 + a) * 32768 + (size_t)h * 32 * 512;
        pB[a] = base + (size_t)(tv * 4 + a) * 32768 + (size_t)h * 32 * 512;
    }

    float4_t acc[4][4];
#pragma unroll
    for (int a = 0; a < 4; a++)
#pragma unroll
        for (int b = 0; b < 4; b++) acc[a][b] = (float4_t){0.f, 0.f, 0.f, 0.f};

#pragma unroll 4
    for (int t = 0; t < 32; t++) {
        const int koff = t * 512;
        long af[4], bf[4];
#pragma unroll
        for (int a = 0; a < 4; a++) {
            af[a] = *(const long*)(pA[a] + koff);
            bf[a] = *(const long*)(pB[a] + koff);
        }
#pragma unroll
        for (int a = 0; a < 4; a++)
#pragma unroll
            for (int b = 0; b < 4; b++)
                acc[a][b] = __builtin_amdgcn_mfma_f32_16x16x32_fp8_fp8(
                    af[a], bf[b], acc[a][b], 0, 0, 0);
    }

    // ---- combine halves + epilogue ----
    if (h == 1) {
#pragma unroll
        for (int a = 0; a < 4; a++)
#pragma unroll
            for (int b = 0; b < 4; b++)
                *(float4_t*)&ep[((a * 4 + b) * 64 + lane) * 4] = acc[a][b];
    }
    __syncthreads();
    if (h == 0) {
        const int lhi = lane >> 4, llo = lane & 15;
        u16* outp = pd + (size_t)p * B_ * B_;
        float rs[4][4];
        float cs[4];
#pragma unroll
        for (int a = 0; a < 4; a++)
#pragma unroll
            for (int r = 0; r < 4; r++) rs[a][r] = 0.f;
#pragma unroll
        for (int b = 0; b < 4; b++) cs[b] = 0.f;
#pragma unroll
        for (int a = 0; a < 4; a++) {
            int la0 = labA[a * 16 + lhi * 4 + 0];
            int la1 = labA[a * 16 + lhi * 4 + 1];
            int la2 = labA[a * 16 + lhi * 4 + 2];
            int la3 = labA[a * 16 + lhi * 4 + 3];
#pragma unroll
            for (int b = 0; b < 4; b++) {
                float4_t o = *(const float4_t*)&ep[((a * 4 + b) * 64 + lane) * 4];
                int jl = b * 16 + llo;
                int lb = labB[jl];
#pragma unroll
                for (int r = 0; r < 4; r++) {
                    int il = a * 16 + lhi * 4 + r;
                    float t = acc[a][b][r] + o[r];
                    float d2 = sqAs[il] + sqBs[jl] - 2.0f * t;
                    outp[(size_t)(i0 + il) * B_ + (j0 + jl)] =
                        __bfloat16_as_ushort(__float2bfloat16(sqrtf(fmaxf(d2, EPS_))));
                    int la = (r == 0) ? la0 : (r == 1) ? la1 : (r == 2) ? la2 : la3;
                    if (lb == la) {
                        rs[a][r] += t;
                        cs[b] += t;
                    }
                }
            }
        }
        // row sums -> S[i0+il]
#pragma unroll
        for (int a = 0; a < 4; a++)
#pragma unroll
            for (int r = 0; r < 4; r++) {
                float v = rs[a][r];
                v += __shfl_xor(v, 1, 64);
                v += __shfl_xor(v, 2, 64);
                v += __shfl_xor(v, 4, 64);
                v += __shfl_xor(v, 8, 64);
                if (llo == 0)
                    atomicAdd(&S[(size_t)(i0 + a * 16 + lhi * 4 + r) * 8 + p], v);
            }
        // col sums -> S[j0+jl] (symmetric contribution) for off-diagonal tiles
        if (tv > tu) {
#pragma unroll
            for (int b = 0; b < 4; b++) {
                float v = cs[b];
                v += __shfl_xor(v, 16, 64);
                v += __shfl_xor(v, 32, 64);
                if (lhi == 0)
                    atomicAdd(&S[(size_t)(j0 + b * 16 + llo) * 8 + p], v);
            }
        }
    }
}

// ---------------- kernel 3: d_ap from Gram row sums ----------------
__global__ void k_dap(const float* __restrict__ S, const float* __restrict__ sq,
                      const float* __restrict__ countsf, const int* __restrict__ offs,
                      const int* __restrict__ perm, float* __restrict__ dap) {
    int c = blockIdx.x;
    int tid = threadIdx.x;
    int cnt = (int)countsf[c];
    int off = offs[c];
    __shared__ float T[8];
    if (tid < 8) {
        float t = 0.f;
        for (int m = 0; m < cnt; m++) t += S[(size_t)perm[off + m] * 8 + tid];
        T[tid] = t;
    }
    __syncthreads();
    float n = fmaxf((float)cnt, 1.f);
    float inv = 1.f / n, inv2 = inv * inv;
    for (int m = tid; m < cnt; m += 64) {
        int i = perm[off + m];
        float d = 0.f;
#pragma unroll
        for (int p = 0; p < 8; p++) {
            float d2 = sq[i * 8 + p] - 2.f * inv * S[(size_t)i * 8 + p] + inv2 * T[p];
            d += sqrtf(fmaxf(d2, EPS_));
        }
        dap[i] = d;
    }
}

// ---------------- kernel 4: masked margin reduction (triangle, x2) + finalize --------
__global__ void k_lossred(const u16* __restrict__ pd, const float* __restrict__ dap,
                          const int* __restrict__ labels, float* possum,
                          const float* negcnt, int* ticket, float* out) {
    int i = blockIdx.x;
    int tid = threadIdx.x;
    float di = dap[i];
    int li = labels[i];
    float lsum = 0.f;
    for (int j = i + 1 + tid; j < B_; j += 256) {
        if (labels[j] != li) {
            float daa = 0.f;
#pragma unroll
            for (int p = 0; p < 8; p++)
                daa += bf2f(pd[((size_t)p << 20) + (size_t)i * B_ + j]);
            lsum += fmaxf(di + dap[j] - daa + MARGIN_, 0.f);
        }
    }
    lsum *= 2.0f;  // symmetric: ordered-pair sum = 2x triangle sum
    for (int o = 32; o; o >>= 1) lsum += __shfl_down(lsum, o, 64);
    __shared__ float red[4];
    int wid = tid >> 6, lane = tid & 63;
    if (lane == 0) red[wid] = lsum;
    __syncthreads();
    if (tid == 0) {
        atomicAdd(possum, red[0] + red[1] + red[2] + red[3]);
        __threadfence();
        int t = atomicAdd(ticket, 1);
        if (t == B_ - 1) {
            float total = atomicAdd(possum, 0.0f);  // atomic read of final sum
            out[0] = total / negcnt[0];
        }
    }
}

// ---------------- launch ----------------
extern "C" void kernel_launch(void* const* d_in, const int* in_sizes, int n_in,
                              void* d_out, int out_size, void* d_ws, size_t ws_size,
                              hipStream_t stream) {
    const float* feats = (const float*)d_in[0];
    const int* labels  = (const int*)d_in[1];
    float* out = (float*)d_out;

    char* w = (char*)d_ws;
    float* countsf = (float*)(w + OFF_COUNTS);
    int* offs      = (int*)(w + OFF_OFFS);
    int* perm      = (int*)(w + OFF_PERM);
    float* negcnt  = (float*)(w + OFF_NEG);
    float* possum  = (float*)(w + OFF_POS);
    int* ticket    = (int*)(w + OFF_TICKET);
    float* S       = (float*)(w + OFF_S);
    float* sq      = (float*)(w + OFF_SQ);
    float* dap     = (float*)(w + OFF_DAP);
    unsigned char* fb = (unsigned char*)(w + OFF_FB);
    u16* pd        = (u16*)(w + OFF_PD);

    // zero possum + ticket + S in one memset
    hipMemsetAsync(w + OFF_POS, 0, (OFF_S - OFF_POS) + (size_t)B_ * P_ * 4, stream);

    k_prep<<<513, 256, 0, stream>>>(feats, labels, fb, sq, countsf, offs, perm, negcnt);
    k_pairs<<<dim3(8, 136), 128, 0, stream>>>(fb, sq, labels, S, pd);
    k_dap<<<NID, 64, 0, stream>>>(S, sq, countsf, offs, perm, dap);
    k_lossred<<<B_, 256, 0, stream>>>(pd, dap, labels, possum, negcnt, ticket, out);
}